// Round 3
// baseline (12589.500 us; speedup 1.0000x reference)
//
#include <hip/hip_runtime.h>
#include <math.h>

// GRU: B=64, S=512, I=256, H=1024, O=256.
// Round 6: move the sync path off HBM and out of block-wide lockstep.
//   - R5 counters: WRITE_SIZE 130MB == exchange stores (sc0sc1 write-through
//     to HBM); FETCH_SIZE 588MB == sc0sc1 flag POLLS going to HBM (~1us each,
//     ~2-4us detect per phase). Poll now uses agent-acquire fence (buffer_inv)
//     + PLAIN cacheable load -> served by Infinity Cache (~0.4us), no HBM
//     traffic. The last poll's fence doubles as the acquire for data loads.
//   - Per-wave band flags: wave w of any block only consumes batch rows
//     [16w,16w+16), written by wave w of all blocks. 256 ushort flags; wave w
//     polls its 64-flag band = ONE 128B line. No __syncthreads in the loop,
//     bands are 4 independent 64-wave barriers (less skew). No s_sleep
//     (hard spin throttled by load latency; keeps clocks up vs DVFS drops).
//   - Store-drain hidden: issue exchange stores, then compute the NEXT
//     phase's x-projection MFMAs, then vmcnt(0) + flag post.

#define KP 1288   // LDS K-stride (elems): 2576 B, 16B aligned

typedef __attribute__((ext_vector_type(8))) short bf8;
typedef __attribute__((ext_vector_type(4))) short bf4;
typedef __attribute__((ext_vector_type(4))) float f32x4;

__device__ __forceinline__ short f2b(float f) {
  unsigned u = __builtin_bit_cast(unsigned, f);
  u += 0x7fffu + ((u >> 16) & 1u);          // RNE
  return (short)(u >> 16);
}
__device__ __forceinline__ float sigm(float x) { return 1.f / (1.f + __expf(-x)); }
__device__ __forceinline__ float tanh_(float x) {
  float t = fminf(fmaxf(x, -12.f), 12.f);
  float e = __expf(2.f * t);
  return (e - 1.f) / (e + 1.f);
}

// ---- LLC write-through stores (visible at coherence point cross-XCD) ----
__device__ __forceinline__ void st_b128_llc(short* p, bf8 v) {
  asm volatile("global_store_dwordx4 %0, %1, off sc0 sc1"
               :: "v"(p), "v"(v) : "memory");
}
__device__ __forceinline__ void st_f32_llc(float* p, float v) {
  asm volatile("global_store_dword %0, %1, off sc0 sc1"
               :: "v"(p), "v"(v) : "memory");
}
__device__ __forceinline__ void st_u16_llc(unsigned short* p, int v) {
  asm volatile("global_store_short %0, %1, off sc0 sc1"
               :: "v"(p), "v"(v) : "memory");
}
__device__ __forceinline__ void drain_vm() {
  asm volatile("s_waitcnt vmcnt(0)" ::: "memory");
}
// Poll: invalidate L1/L2, plain load (IF$-served), check band complete.
// The fence of the successful iteration is the acquire for the data loads.
__device__ __forceinline__ void waitband(const unsigned short* fp, int p) {
  const volatile unsigned short* f = fp;
  for (;;) {
    __builtin_amdgcn_fence(__ATOMIC_ACQUIRE, "agent");   // buffer_inv
    int v = *f;
    if (__all(v >= p)) break;
  }
}

#define MFMA __builtin_amdgcn_mfma_f32_16x16x32_bf16

// ---------------- preprocessing ----------------

__global__ __launch_bounds__(256) void cvt_x(const float* __restrict__ in,
                                             short* __restrict__ outp) {
  int idx = blockIdx.x * 256 + threadIdx.x;        // 8192 blocks, 4 floats each
  float4 v = ((const float4*)in)[idx];
  bf4 o;
  o[0] = f2b(v.x); o[1] = f2b(v.y); o[2] = f2b(v.z); o[3] = f2b(v.w);
  ((bf4*)outp)[idx] = o;
}

// Wt[g][j][k] = bf16( k<1024 ? Wh_g[k][j] : Wx_g[k-1024][j] ), k=0..1279.
__global__ __launch_bounds__(256) void pack_w(
    const float* __restrict__ Whz, const float* __restrict__ Wxz,
    const float* __restrict__ Whr, const float* __restrict__ Wxr,
    const float* __restrict__ Whh, const float* __restrict__ Wxh,
    short* __restrict__ Wt) {
  int b = blockIdx.x;
  int g = b / 320, rem = b % 320;
  int jt = rem / 20, kt = rem % 20;
  int j0 = jt * 64, k0 = kt * 64;
  const float* Wh = (g == 0) ? Whz : (g == 1) ? Whr : Whh;
  const float* Wx = (g == 0) ? Wxz : (g == 1) ? Wxr : Wxh;
  __shared__ short tile[64 * 72];
  int tid = threadIdx.x;
  for (int p = 0; p < 16; ++p) {
    int r = p * 4 + (tid >> 6);
    int cc = tid & 63;
    int k = k0 + r;
    float v = (k < 1024) ? Wh[(size_t)k * 1024 + j0 + cc]
                         : Wx[(size_t)(k - 1024) * 1024 + j0 + cc];
    tile[r * 72 + cc] = f2b(v);
  }
  __syncthreads();
  int j = tid >> 2, kq = tid & 3;
  bf8 v0, v1;
#pragma unroll
  for (int i = 0; i < 8; ++i) {
    v0[i] = tile[(kq * 16 + i) * 72 + j];
    v1[i] = tile[(kq * 16 + 8 + i) * 72 + j];
  }
  short* dst = Wt + ((size_t)(g * 1024 + j0 + j)) * 1280 + k0 + kq * 16;
  *(bf8*)dst = v0;
  *((bf8*)dst + 1) = v1;
}

// ---------------- persistent GRU kernel ----------------
__global__ __launch_bounds__(256, 1) void gru_persistent(
    const short* __restrict__ xx,   // x bf16 [64][512][256]
    const short* __restrict__ Wt,   // packed weights bf16 [3][1024][1280]
    float* __restrict__ h32,        // fp32 h final [64][1024] (written s=511)
    short* __restrict__ h16,        // bf16 h (exchange)
    short* __restrict__ ab,         // bf16 r*h (exchange)
    unsigned short* __restrict__ flags,  // 256 per-wave flags [band][block]
    const float* __restrict__ bz, const float* __restrict__ br,
    const float* __restrict__ bh,
    const float* __restrict__ Wf, const float* __restrict__ bfv,
    float* __restrict__ out) {
  extern __shared__ short lds[];                 // 48*KP weights + 4*256 scratch

  const int tid = threadIdx.x;
  const int w = tid >> 6, lane = tid & 63;
  const int row16 = lane & 15, quad = lane >> 4;
  const int j0 = blockIdx.x * 16;
  const int bg0 = w * 16;
  const int bA = bg0 + row16;                    // batch row for A-loads

  const float bzv = bz[j0 + row16];
  const float brv = br[j0 + row16];
  const float bhv = bh[j0 + row16];

  // weights -> LDS (48 cols x 1280, transposed, bf16)
  for (int ch = tid; ch < 48 * 160; ch += 256) {
    int lc = ch / 160, c8 = ch % 160;
    int g = lc >> 4, j = j0 + (lc & 15);
    *(bf8*)(lds + lc * KP + c8 * 8) =
        *(const bf8*)(Wt + ((size_t)(g * 1024 + j)) * 1280 + c8 * 8);
  }
  __syncthreads();                               // only block-wide sync

  const short* wzp = lds + row16 * KP;
  const short* wrp = lds + (16 + row16) * KP;
  const short* wnp = lds + (32 + row16) * KP;
  short* sc = lds + 48 * KP + w * 256;           // wave-private 16x16 tile
  const int ko = quad * 8;

  const unsigned short* fband = flags + w * 64 + lane;   // band poll addr
  unsigned short* myflag = flags + w * 64 + blockIdx.x;

  float hreg[4] = {0.f, 0.f, 0.f, 0.f};          // fp32 h, lives in regs
  float zreg[4];

  // prologue: x-projection of step 0 (z, r)
  f32x4 az0 = {0.f,0.f,0.f,0.f}, ar0 = {0.f,0.f,0.f,0.f};
  {
    const short* xrow = xx + (bA * 512) * 256 - 1024;
#pragma unroll
    for (int kt = 32; kt < 40; ++kt) {
      int k = kt * 32 + ko;
      bf8 a = *(const bf8*)(xrow + k);
      az0 = MFMA(a, *(const bf8*)(wzp + k), az0, 0, 0, 0);
      ar0 = MFMA(a, *(const bf8*)(wrp + k), ar0, 0, 0, 0);
    }
  }

  for (int s = 0; s < 512; ++s) {
    const short* xrow = xx + (bA * 512 + s) * 256 - 1024;  // +k valid k>=1024

    // ---------- phase 1: z, r (x-part already in az0/ar0) ----------
    f32x4 az1 = {0.f,0.f,0.f,0.f}, ar1 = {0.f,0.f,0.f,0.f};
    waitband(fband, 2 * s);                      // band's h16(s-1) at LLC
    {
      const short* hb = h16 + bA * 1024 + ko;
      bf8 a[32];
#pragma unroll
      for (int t = 0; t < 32; ++t) a[t] = *(const bf8*)(hb + t * 32);
#pragma unroll
      for (int t = 0; t < 32; t += 2) {
        int k0 = t * 32 + ko, k1 = k0 + 32;
        az0 = MFMA(a[t],     *(const bf8*)(wzp + k0), az0, 0, 0, 0);
        az1 = MFMA(a[t + 1], *(const bf8*)(wzp + k1), az1, 0, 0, 0);
        ar0 = MFMA(a[t],     *(const bf8*)(wrp + k0), ar0, 0, 0, 0);
        ar1 = MFMA(a[t + 1], *(const bf8*)(wrp + k1), ar1, 0, 0, 0);
      }
    }
    f32x4 azs = az0 + az1, ars = ar0 + ar1;
#pragma unroll
    for (int i = 0; i < 4; ++i) {
      zreg[i] = sigm(azs[i] + bzv);
      float r = sigm(ars[i] + brv);
      sc[(quad * 4 + i) * 16 + row16] = f2b(r * hreg[i]);  // wave-local LDS
    }
    if (lane < 32) {                             // same wave: in-order, no bar
      int rr = lane >> 1, hh = lane & 1;
      bf8 v = *(const bf8*)(sc + rr * 16 + hh * 8);
      st_b128_llc(ab + (bg0 + rr) * 1024 + j0 + hh * 8, v);
    }
    // x-projection for n — overlaps the store drain
    f32x4 an0 = {0.f,0.f,0.f,0.f}, an1 = {0.f,0.f,0.f,0.f};
#pragma unroll
    for (int kt = 32; kt < 40; ++kt) {
      int k = kt * 32 + ko;
      bf8 a = *(const bf8*)(xrow + k);
      an0 = MFMA(a, *(const bf8*)(wnp + k), an0, 0, 0, 0);
    }
    drain_vm();                                  // ab stores (+x loads) done
    if (lane == 0) st_u16_llc(myflag, 2 * s + 1);

    // ---------- phase 2: n, h update ----------
    waitband(fband, 2 * s + 1);                  // band's ab(s) at LLC
    {
      const short* abb = ab + bA * 1024 + ko;
      bf8 a[32];
#pragma unroll
      for (int t = 0; t < 32; ++t) a[t] = *(const bf8*)(abb + t * 32);
#pragma unroll
      for (int t = 0; t < 32; t += 2) {
        int k0 = t * 32 + ko, k1 = k0 + 32;
        an0 = MFMA(a[t],     *(const bf8*)(wnp + k0), an0, 0, 0, 0);
        an1 = MFMA(a[t + 1], *(const bf8*)(wnp + k1), an1, 0, 0, 0);
      }
    }
    f32x4 ans = an0 + an1;
#pragma unroll
    for (int i = 0; i < 4; ++i) {
      float n = tanh_(ans[i] + bhv);
      hreg[i] = fmaf(zreg[i], n - hreg[i], hreg[i]);   // (1-z)h + z*n
      sc[(quad * 4 + i) * 16 + row16] = f2b(hreg[i]);
      if (s == 511)
        st_f32_llc(&h32[(bg0 + quad * 4 + i) * 1024 + j0 + row16], hreg[i]);
    }
    if (lane < 32) {
      int rr = lane >> 1, hh = lane & 1;
      bf8 v = *(const bf8*)(sc + rr * 16 + hh * 8);
      st_b128_llc(h16 + (bg0 + rr) * 1024 + j0 + hh * 8, v);
    }
    // x-projection for next step's z,r — overlaps the store drain
    if (s < 511) {
      const short* xr2 = xrow + 256;             // step s+1
      az0 = (f32x4){0.f,0.f,0.f,0.f};
      ar0 = (f32x4){0.f,0.f,0.f,0.f};
#pragma unroll
      for (int kt = 32; kt < 40; ++kt) {
        int k = kt * 32 + ko;
        bf8 a = *(const bf8*)(xr2 + k);
        az0 = MFMA(a, *(const bf8*)(wzp + k), az0, 0, 0, 0);
        ar0 = MFMA(a, *(const bf8*)(wrp + k), ar0, 0, 0, 0);
      }
    }
    drain_vm();                                  // h16 (+h32) stores done
    if (lane == 0) st_u16_llc(myflag, 2 * s + 2);
  }

  // ---------- head: out[b][o] = sum_k h32[b][k]*Wf[k][o] + bf[o] ----------
  waitband(flags + ((blockIdx.x >> 4) << 6) + lane, 1024);  // h32 band ready
  {
    const float* hrow = h32 + blockIdx.x * 1024;
    float acc = bfv[tid];
#pragma unroll 8
    for (int k = 0; k < 1024; ++k)
      acc = fmaf(hrow[k], Wf[(size_t)k * 256 + tid], acc);
    out[blockIdx.x * 256 + tid] = acc;
  }
}

// ---------------- host ----------------
extern "C" void kernel_launch(void* const* d_in, const int* in_sizes, int n_in,
                              void* d_out, int out_size, void* d_ws, size_t ws_size,
                              hipStream_t stream) {
  const float* x   = (const float*)d_in[0];
  const float* Wxz = (const float*)d_in[1];
  const float* Whz = (const float*)d_in[2];
  const float* Wxr = (const float*)d_in[3];
  const float* Whr = (const float*)d_in[4];
  const float* Wxh = (const float*)d_in[5];
  const float* Whh = (const float*)d_in[6];
  const float* bz  = (const float*)d_in[7];
  const float* br  = (const float*)d_in[8];
  const float* bh  = (const float*)d_in[9];
  const float* Wf  = (const float*)d_in[10];
  const float* bfp = (const float*)d_in[11];
  float* out = (float*)d_out;

  char* ws = (char*)d_ws;
  float* h32 = (float*)(ws + 0);            // 256 KB
  short* h16 = (short*)(ws + 262144);       // 128 KB
  unsigned short* flg = (unsigned short*)(ws + 393216);  // 512 B used
  short* ab  = (short*)(ws + 397312);       // 128 KB
  short* xx  = (short*)(ws + 528384);       // 16 MB
  short* Wt  = (short*)(ws + 17305600);     // 7.86 MB (total ~24 MB)

  hipMemsetAsync(d_ws, 0, 397312, stream);  // h32 + h16 + flags = zeros

  cvt_x<<<8192, 256, 0, stream>>>(x, xx);
  pack_w<<<960, 256, 0, stream>>>(Whz, Wxz, Whr, Wxr, Whh, Wxh, Wt);

  const int smem = (48 * KP + 4 * 256) * 2; // 125,696 B
  hipFuncSetAttribute((const void*)gru_persistent,
                      hipFuncAttributeMaxDynamicSharedMemorySize, smem);
  void* args[] = {&xx, &Wt, &h32, &h16, &ab, &flg,
                  (void*)&bz, (void*)&br, (void*)&bh, (void*)&Wf, (void*)&bfp, &out};
  hipLaunchCooperativeKernel((const void*)gru_persistent, dim3(64), dim3(256),
                             args, smem, stream);
}

// Round 4
// 11011.528 us; speedup vs baseline: 1.1433x; 1.1433x over previous
//
#include <hip/hip_runtime.h>
#include <math.h>

// GRU: B=64, S=512, I=256, H=1024, O=256.
// Round 7 = R6 skeleton + R5 poll mechanism.
//   - R6 post-mortem: FETCH_SIZE ~600MB is the structural exchange refetch
//     (same in R3/R5/R6), NOT polls. R6's regression was the fence-in-poll
//     loop: 32 waves/XCD spamming buffer_inv evicted the shared L2 under
//     every co-resident wave (VALUBusy 0.98->0.71).
//   - Poll: sc0sc1 ushort load (bypasses L1/L2, reads coherence point, never
//     stale, NO invalidation), band-restricted (wave w polls its 64-flag
//     128B line). ONE acq (buffer_inv) after detect, then plain cacheable
//     burst loads — R5's proven-correct read path.
//   - Kept from R6: per-wave band flags (4 independent 64-wave barriers,
//     no __syncthreads in loop), wave-private LDS transpose, 16B exchange
//     stores, store-drain hidden under next x-projection MFMAs, no s_sleep.

#define KP 1288   // LDS K-stride (elems): 2576 B, 16B aligned

typedef __attribute__((ext_vector_type(8))) short bf8;
typedef __attribute__((ext_vector_type(4))) short bf4;
typedef __attribute__((ext_vector_type(4))) float f32x4;

__device__ __forceinline__ short f2b(float f) {
  unsigned u = __builtin_bit_cast(unsigned, f);
  u += 0x7fffu + ((u >> 16) & 1u);          // RNE
  return (short)(u >> 16);
}
__device__ __forceinline__ float sigm(float x) { return 1.f / (1.f + __expf(-x)); }
__device__ __forceinline__ float tanh_(float x) {
  float t = fminf(fmaxf(x, -12.f), 12.f);
  float e = __expf(2.f * t);
  return (e - 1.f) / (e + 1.f);
}

// ---- LLC write-through stores (visible at coherence point cross-XCD) ----
__device__ __forceinline__ void st_b128_llc(short* p, bf8 v) {
  asm volatile("global_store_dwordx4 %0, %1, off sc0 sc1"
               :: "v"(p), "v"(v) : "memory");
}
__device__ __forceinline__ void st_f32_llc(float* p, float v) {
  asm volatile("global_store_dword %0, %1, off sc0 sc1"
               :: "v"(p), "v"(v) : "memory");
}
__device__ __forceinline__ void st_u16_llc(unsigned short* p, int v) {
  asm volatile("global_store_short %0, %1, off sc0 sc1"
               :: "v"(p), "v"(v) : "memory");
}
__device__ __forceinline__ void drain_vm() {
  asm volatile("s_waitcnt vmcnt(0)" ::: "memory");
}
__device__ __forceinline__ void acq() {
  __builtin_amdgcn_fence(__ATOMIC_ACQUIRE, "agent");   // buffer_inv, ONCE
}
// Band poll: sc0sc1 load straight from the coherence point (no stale risk,
// no cache invalidation). Load+waitcnt inside one asm => value valid.
__device__ __forceinline__ void waitband(const unsigned short* fp, int p) {
  for (;;) {
    int v;
    asm volatile("global_load_ushort %0, %1, off sc0 sc1\n"
                 "s_waitcnt vmcnt(0)"
                 : "=v"(v) : "v"(fp) : "memory");
    if (__all(v >= p)) break;
  }
}

#define MFMA __builtin_amdgcn_mfma_f32_16x16x32_bf16

// ---------------- preprocessing ----------------

__global__ __launch_bounds__(256) void cvt_x(const float* __restrict__ in,
                                             short* __restrict__ outp) {
  int idx = blockIdx.x * 256 + threadIdx.x;        // 8192 blocks, 4 floats each
  float4 v = ((const float4*)in)[idx];
  bf4 o;
  o[0] = f2b(v.x); o[1] = f2b(v.y); o[2] = f2b(v.z); o[3] = f2b(v.w);
  ((bf4*)outp)[idx] = o;
}

// Wt[g][j][k] = bf16( k<1024 ? Wh_g[k][j] : Wx_g[k-1024][j] ), k=0..1279.
__global__ __launch_bounds__(256) void pack_w(
    const float* __restrict__ Whz, const float* __restrict__ Wxz,
    const float* __restrict__ Whr, const float* __restrict__ Wxr,
    const float* __restrict__ Whh, const float* __restrict__ Wxh,
    short* __restrict__ Wt) {
  int b = blockIdx.x;
  int g = b / 320, rem = b % 320;
  int jt = rem / 20, kt = rem % 20;
  int j0 = jt * 64, k0 = kt * 64;
  const float* Wh = (g == 0) ? Whz : (g == 1) ? Whr : Whh;
  const float* Wx = (g == 0) ? Wxz : (g == 1) ? Wxr : Wxh;
  __shared__ short tile[64 * 72];
  int tid = threadIdx.x;
  for (int p = 0; p < 16; ++p) {
    int r = p * 4 + (tid >> 6);
    int cc = tid & 63;
    int k = k0 + r;
    float v = (k < 1024) ? Wh[(size_t)k * 1024 + j0 + cc]
                         : Wx[(size_t)(k - 1024) * 1024 + j0 + cc];
    tile[r * 72 + cc] = f2b(v);
  }
  __syncthreads();
  int j = tid >> 2, kq = tid & 3;
  bf8 v0, v1;
#pragma unroll
  for (int i = 0; i < 8; ++i) {
    v0[i] = tile[(kq * 16 + i) * 72 + j];
    v1[i] = tile[(kq * 16 + 8 + i) * 72 + j];
  }
  short* dst = Wt + ((size_t)(g * 1024 + j0 + j)) * 1280 + k0 + kq * 16;
  *(bf8*)dst = v0;
  *((bf8*)dst + 1) = v1;
}

// ---------------- persistent GRU kernel ----------------
__global__ __launch_bounds__(256, 1) void gru_persistent(
    const short* __restrict__ xx,   // x bf16 [64][512][256]
    const short* __restrict__ Wt,   // packed weights bf16 [3][1024][1280]
    float* __restrict__ h32,        // fp32 h final [64][1024] (written s=511)
    short* __restrict__ h16,        // bf16 h (exchange)
    short* __restrict__ ab,         // bf16 r*h (exchange)
    unsigned short* __restrict__ flags,  // 256 per-wave flags [band][block]
    const float* __restrict__ bz, const float* __restrict__ br,
    const float* __restrict__ bh,
    const float* __restrict__ Wf, const float* __restrict__ bfv,
    float* __restrict__ out) {
  extern __shared__ short lds[];                 // 48*KP weights + 4*256 scratch

  const int tid = threadIdx.x;
  const int w = tid >> 6, lane = tid & 63;
  const int row16 = lane & 15, quad = lane >> 4;
  const int j0 = blockIdx.x * 16;
  const int bg0 = w * 16;
  const int bA = bg0 + row16;                    // batch row for A-loads

  const float bzv = bz[j0 + row16];
  const float brv = br[j0 + row16];
  const float bhv = bh[j0 + row16];

  // weights -> LDS (48 cols x 1280, transposed, bf16)
  for (int ch = tid; ch < 48 * 160; ch += 256) {
    int lc = ch / 160, c8 = ch % 160;
    int g = lc >> 4, j = j0 + (lc & 15);
    *(bf8*)(lds + lc * KP + c8 * 8) =
        *(const bf8*)(Wt + ((size_t)(g * 1024 + j)) * 1280 + c8 * 8);
  }
  __syncthreads();                               // only block-wide sync

  const short* wzp = lds + row16 * KP;
  const short* wrp = lds + (16 + row16) * KP;
  const short* wnp = lds + (32 + row16) * KP;
  short* sc = lds + 48 * KP + w * 256;           // wave-private 16x16 tile
  const int ko = quad * 8;

  const unsigned short* fband = flags + w * 64 + lane;   // band poll addr
  unsigned short* myflag = flags + w * 64 + blockIdx.x;

  float hreg[4] = {0.f, 0.f, 0.f, 0.f};          // fp32 h, lives in regs
  float zreg[4];

  // prologue: x-projection of step 0 (z, r)
  f32x4 az0 = {0.f,0.f,0.f,0.f}, ar0 = {0.f,0.f,0.f,0.f};
  {
    const short* xrow = xx + (bA * 512) * 256 - 1024;
#pragma unroll
    for (int kt = 32; kt < 40; ++kt) {
      int k = kt * 32 + ko;
      bf8 a = *(const bf8*)(xrow + k);
      az0 = MFMA(a, *(const bf8*)(wzp + k), az0, 0, 0, 0);
      ar0 = MFMA(a, *(const bf8*)(wrp + k), ar0, 0, 0, 0);
    }
  }

  for (int s = 0; s < 512; ++s) {
    const short* xrow = xx + (bA * 512 + s) * 256 - 1024;  // +k valid k>=1024

    // ---------- phase 1: z, r (x-part already in az0/ar0) ----------
    f32x4 az1 = {0.f,0.f,0.f,0.f}, ar1 = {0.f,0.f,0.f,0.f};
    waitband(fband, 2 * s);                      // band's h16(s-1) at LLC
    acq();                                       // ONE invalidate post-detect
    {
      const short* hb = h16 + bA * 1024 + ko;
      bf8 a[32];
#pragma unroll
      for (int t = 0; t < 32; ++t) a[t] = *(const bf8*)(hb + t * 32);
#pragma unroll
      for (int t = 0; t < 32; t += 2) {
        int k0 = t * 32 + ko, k1 = k0 + 32;
        az0 = MFMA(a[t],     *(const bf8*)(wzp + k0), az0, 0, 0, 0);
        az1 = MFMA(a[t + 1], *(const bf8*)(wzp + k1), az1, 0, 0, 0);
        ar0 = MFMA(a[t],     *(const bf8*)(wrp + k0), ar0, 0, 0, 0);
        ar1 = MFMA(a[t + 1], *(const bf8*)(wrp + k1), ar1, 0, 0, 0);
      }
    }
    f32x4 azs = az0 + az1, ars = ar0 + ar1;
#pragma unroll
    for (int i = 0; i < 4; ++i) {
      zreg[i] = sigm(azs[i] + bzv);
      float r = sigm(ars[i] + brv);
      sc[(quad * 4 + i) * 16 + row16] = f2b(r * hreg[i]);  // wave-local LDS
    }
    if (lane < 32) {                             // same wave: in-order, no bar
      int rr = lane >> 1, hh = lane & 1;
      bf8 v = *(const bf8*)(sc + rr * 16 + hh * 8);
      st_b128_llc(ab + (bg0 + rr) * 1024 + j0 + hh * 8, v);
    }
    // x-projection for n — overlaps the store drain
    f32x4 an0 = {0.f,0.f,0.f,0.f}, an1 = {0.f,0.f,0.f,0.f};
#pragma unroll
    for (int kt = 32; kt < 40; ++kt) {
      int k = kt * 32 + ko;
      bf8 a = *(const bf8*)(xrow + k);
      an0 = MFMA(a, *(const bf8*)(wnp + k), an0, 0, 0, 0);
    }
    drain_vm();                                  // ab stores (+x loads) done
    if (lane == 0) st_u16_llc(myflag, 2 * s + 1);

    // ---------- phase 2: n, h update ----------
    waitband(fband, 2 * s + 1);                  // band's ab(s) at LLC
    acq();
    {
      const short* abb = ab + bA * 1024 + ko;
      bf8 a[32];
#pragma unroll
      for (int t = 0; t < 32; ++t) a[t] = *(const bf8*)(abb + t * 32);
#pragma unroll
      for (int t = 0; t < 32; t += 2) {
        int k0 = t * 32 + ko, k1 = k0 + 32;
        an0 = MFMA(a[t],     *(const bf8*)(wnp + k0), an0, 0, 0, 0);
        an1 = MFMA(a[t + 1], *(const bf8*)(wnp + k1), an1, 0, 0, 0);
      }
    }
    f32x4 ans = an0 + an1;
#pragma unroll
    for (int i = 0; i < 4; ++i) {
      float n = tanh_(ans[i] + bhv);
      hreg[i] = fmaf(zreg[i], n - hreg[i], hreg[i]);   // (1-z)h + z*n
      sc[(quad * 4 + i) * 16 + row16] = f2b(hreg[i]);
      if (s == 511)
        st_f32_llc(&h32[(bg0 + quad * 4 + i) * 1024 + j0 + row16], hreg[i]);
    }
    if (lane < 32) {
      int rr = lane >> 1, hh = lane & 1;
      bf8 v = *(const bf8*)(sc + rr * 16 + hh * 8);
      st_b128_llc(h16 + (bg0 + rr) * 1024 + j0 + hh * 8, v);
    }
    // x-projection for next step's z,r — overlaps the store drain
    if (s < 511) {
      const short* xr2 = xrow + 256;             // step s+1
      az0 = (f32x4){0.f,0.f,0.f,0.f};
      ar0 = (f32x4){0.f,0.f,0.f,0.f};
#pragma unroll
      for (int kt = 32; kt < 40; ++kt) {
        int k = kt * 32 + ko;
        bf8 a = *(const bf8*)(xr2 + k);
        az0 = MFMA(a, *(const bf8*)(wzp + k), az0, 0, 0, 0);
        ar0 = MFMA(a, *(const bf8*)(wrp + k), ar0, 0, 0, 0);
      }
    }
    drain_vm();                                  // h16 (+h32) stores done
    if (lane == 0) st_u16_llc(myflag, 2 * s + 2);
  }

  // ---------- head: out[b][o] = sum_k h32[b][k]*Wf[k][o] + bf[o] ----------
  waitband(flags + ((blockIdx.x >> 4) << 6) + lane, 1024);  // h32 band ready
  acq();
  {
    const float* hrow = h32 + blockIdx.x * 1024;
    float acc = bfv[tid];
#pragma unroll 8
    for (int k = 0; k < 1024; ++k)
      acc = fmaf(hrow[k], Wf[(size_t)k * 256 + tid], acc);
    out[blockIdx.x * 256 + tid] = acc;
  }
}

// ---------------- host ----------------
extern "C" void kernel_launch(void* const* d_in, const int* in_sizes, int n_in,
                              void* d_out, int out_size, void* d_ws, size_t ws_size,
                              hipStream_t stream) {
  const float* x   = (const float*)d_in[0];
  const float* Wxz = (const float*)d_in[1];
  const float* Whz = (const float*)d_in[2];
  const float* Wxr = (const float*)d_in[3];
  const float* Whr = (const float*)d_in[4];
  const float* Wxh = (const float*)d_in[5];
  const float* Whh = (const float*)d_in[6];
  const float* bz  = (const float*)d_in[7];
  const float* br  = (const float*)d_in[8];
  const float* bh  = (const float*)d_in[9];
  const float* Wf  = (const float*)d_in[10];
  const float* bfp = (const float*)d_in[11];
  float* out = (float*)d_out;

  char* ws = (char*)d_ws;
  float* h32 = (float*)(ws + 0);            // 256 KB
  short* h16 = (short*)(ws + 262144);       // 128 KB
  unsigned short* flg = (unsigned short*)(ws + 393216);  // 512 B used
  short* ab  = (short*)(ws + 397312);       // 128 KB
  short* xx  = (short*)(ws + 528384);       // 16 MB
  short* Wt  = (short*)(ws + 17305600);     // 7.86 MB (total ~24 MB)

  hipMemsetAsync(d_ws, 0, 397312, stream);  // h32 + h16 + flags = zeros

  cvt_x<<<8192, 256, 0, stream>>>(x, xx);
  pack_w<<<960, 256, 0, stream>>>(Whz, Wxz, Whr, Wxr, Whh, Wxh, Wt);

  const int smem = (48 * KP + 4 * 256) * 2; // 125,696 B
  hipFuncSetAttribute((const void*)gru_persistent,
                      hipFuncAttributeMaxDynamicSharedMemorySize, smem);
  void* args[] = {&xx, &Wt, &h32, &h16, &ab, &flg,
                  (void*)&bz, (void*)&br, (void*)&bh, (void*)&Wf, (void*)&bfp, &out};
  hipLaunchCooperativeKernel((const void*)gru_persistent, dim3(64), dim3(256),
                             args, smem, stream);
}

// Round 5
// 8006.280 us; speedup vs baseline: 1.5725x; 1.3754x over previous
//
#include <hip/hip_runtime.h>
#include <math.h>

// GRU: B=64, S=512, I=256, H=1024, O=256.
// Round 8 = R5 skeleton (proven 8624us) + three latency cuts. Lessons:
//   - R7: never put work between exchange stores and the flag post — it adds
//     directly to the 1024-round global serial chain. x-proj belongs at phase
//     START (inside the detect window).
//   - R6: never fence inside a poll loop (L2 invalidation storm).
//   - New here:
//     (1) guaranteed 32-deep exchange read burst: plain loads into a[32],
//         then sched_barrier(0) before MFMAs -> one LLC RTT, compiler-safe
//         (no R4-style asm-output register hazard).
//     (2) pipelined flag poll in ONE asm block: next poll load issued while
//         checking the previous (v_cmp + s_cbranch_vccz) -> detect ~1 RTT.
//     (3) 4 MFMA accumulators per gate (dep chain 16->8); first syncthreads
//         dropped (sc tile is wave-private; same-wave DS ops are in-order).

#define KP 1288   // LDS K-stride (elems): 2576 B, 16B aligned

typedef __attribute__((ext_vector_type(8))) short bf8;
typedef __attribute__((ext_vector_type(4))) short bf4;
typedef __attribute__((ext_vector_type(4))) float f32x4;

__device__ __forceinline__ short f2b(float f) {
  unsigned u = __builtin_bit_cast(unsigned, f);
  u += 0x7fffu + ((u >> 16) & 1u);          // RNE
  return (short)(u >> 16);
}
__device__ __forceinline__ float sigm(float x) { return 1.f / (1.f + __expf(-x)); }
__device__ __forceinline__ float tanh_(float x) {
  float t = fminf(fmaxf(x, -12.f), 12.f);
  float e = __expf(2.f * t);
  return (e - 1.f) / (e + 1.f);
}

// ---- LLC write-through stores (visible at coherence point cross-XCD) ----
__device__ __forceinline__ void st_b128_llc(short* p, bf8 v) {
  asm volatile("global_store_dwordx4 %0, %1, off sc0 sc1"
               :: "v"(p), "v"(v) : "memory");
}
__device__ __forceinline__ void st_f32_llc(float* p, float v) {
  asm volatile("global_store_dword %0, %1, off sc0 sc1"
               :: "v"(p), "v"(v) : "memory");
}
__device__ __forceinline__ void st_i32_llc(int* p, int v) {
  asm volatile("global_store_dword %0, %1, off sc0 sc1"
               :: "v"(p), "v"(v) : "memory");
}
__device__ __forceinline__ void drain_vm() {
  asm volatile("s_waitcnt vmcnt(0)" ::: "memory");
}
__device__ __forceinline__ void acq() {
  __builtin_amdgcn_fence(__ATOMIC_ACQUIRE, "agent");   // buffer_inv, ONCE
}
// Pipelined poll, fully inside one asm block (compiler cannot spill in-flight
// asm outputs — the R4 bug class). Two poll loads in flight; check one while
// the other travels. sc0sc1 loads read the coherence point (never stale, no
// cache invalidation). Exit: all 64 lanes' flags >= p.
__device__ __forceinline__ void waitflags(const int* fp, int p) {
  int f0, f1;
  asm volatile(
      "global_load_dword %0, %2, off sc0 sc1\n"
      "1:\n"
      "global_load_dword %1, %2, off sc0 sc1\n"
      "s_waitcnt vmcnt(1)\n"
      "v_cmp_lt_i32 vcc, %0, %3\n"
      "s_cbranch_vccz 2f\n"
      "global_load_dword %0, %2, off sc0 sc1\n"
      "s_waitcnt vmcnt(1)\n"
      "v_cmp_lt_i32 vcc, %1, %3\n"
      "s_cbranch_vccz 2f\n"
      "s_branch 1b\n"
      "2:\n"
      "s_waitcnt vmcnt(0)\n"
      : "=&v"(f0), "=&v"(f1)
      : "v"(fp), "v"(p)
      : "vcc", "memory");
}

#define MFMA __builtin_amdgcn_mfma_f32_16x16x32_bf16

// ---------------- preprocessing ----------------

__global__ __launch_bounds__(256) void cvt_x(const float* __restrict__ in,
                                             short* __restrict__ outp) {
  int idx = blockIdx.x * 256 + threadIdx.x;        // 8192 blocks, 4 floats each
  float4 v = ((const float4*)in)[idx];
  bf4 o;
  o[0] = f2b(v.x); o[1] = f2b(v.y); o[2] = f2b(v.z); o[3] = f2b(v.w);
  ((bf4*)outp)[idx] = o;
}

// Wt[g][j][k] = bf16( k<1024 ? Wh_g[k][j] : Wx_g[k-1024][j] ), k=0..1279.
__global__ __launch_bounds__(256) void pack_w(
    const float* __restrict__ Whz, const float* __restrict__ Wxz,
    const float* __restrict__ Whr, const float* __restrict__ Wxr,
    const float* __restrict__ Whh, const float* __restrict__ Wxh,
    short* __restrict__ Wt) {
  int b = blockIdx.x;
  int g = b / 320, rem = b % 320;
  int jt = rem / 20, kt = rem % 20;
  int j0 = jt * 64, k0 = kt * 64;
  const float* Wh = (g == 0) ? Whz : (g == 1) ? Whr : Whh;
  const float* Wx = (g == 0) ? Wxz : (g == 1) ? Wxr : Wxh;
  __shared__ short tile[64 * 72];
  int tid = threadIdx.x;
  for (int p = 0; p < 16; ++p) {
    int r = p * 4 + (tid >> 6);
    int cc = tid & 63;
    int k = k0 + r;
    float v = (k < 1024) ? Wh[(size_t)k * 1024 + j0 + cc]
                         : Wx[(size_t)(k - 1024) * 1024 + j0 + cc];
    tile[r * 72 + cc] = f2b(v);
  }
  __syncthreads();
  int j = tid >> 2, kq = tid & 3;
  bf8 v0, v1;
#pragma unroll
  for (int i = 0; i < 8; ++i) {
    v0[i] = tile[(kq * 16 + i) * 72 + j];
    v1[i] = tile[(kq * 16 + 8 + i) * 72 + j];
  }
  short* dst = Wt + ((size_t)(g * 1024 + j0 + j)) * 1280 + k0 + kq * 16;
  *(bf8*)dst = v0;
  *((bf8*)dst + 1) = v1;
}

// ---------------- persistent GRU kernel ----------------
__global__ __launch_bounds__(256, 1) void gru_persistent(
    const short* __restrict__ xx,   // x bf16 [64][512][256]
    const short* __restrict__ Wt,   // packed weights bf16 [3][1024][1280]
    float* __restrict__ h32,        // fp32 h final [64][1024] (written s=511)
    short* __restrict__ h16,        // bf16 h (exchange)
    short* __restrict__ ab,         // bf16 r*h (exchange)
    int* __restrict__ flags,        // 64 per-block progress flags
    const float* __restrict__ bz, const float* __restrict__ br,
    const float* __restrict__ bh,
    const float* __restrict__ Wf, const float* __restrict__ bfv,
    float* __restrict__ out) {
  extern __shared__ short lds[];                 // 48*KP weights + 4*256 scratch

  const int tid = threadIdx.x;
  const int w = tid >> 6, lane = tid & 63;
  const int row16 = lane & 15, quad = lane >> 4;
  const int j0 = blockIdx.x * 16;
  const int bg0 = w * 16;
  const int bA = bg0 + row16;                    // batch row for A-loads

  const float bzv = bz[j0 + row16];
  const float brv = br[j0 + row16];
  const float bhv = bh[j0 + row16];

  // weights -> LDS (48 cols x 1280, transposed, bf16)
  for (int ch = tid; ch < 48 * 160; ch += 256) {
    int lc = ch / 160, c8 = ch % 160;
    int g = lc >> 4, j = j0 + (lc & 15);
    *(bf8*)(lds + lc * KP + c8 * 8) =
        *(const bf8*)(Wt + ((size_t)(g * 1024 + j)) * 1280 + c8 * 8);
  }
  __syncthreads();

  const short* wzp = lds + row16 * KP;
  const short* wrp = lds + (16 + row16) * KP;
  const short* wnp = lds + (32 + row16) * KP;
  short* sc = lds + 48 * KP + w * 256;           // wave-private 16x16 tile
  const int ko = quad * 8;

  float hreg[4] = {0.f, 0.f, 0.f, 0.f};          // fp32 h, lives in regs
  float zreg[4];

  for (int s = 0; s < 512; ++s) {
    const short* xrow = xx + (bA * 512 + s) * 256 - 1024;  // +k valid k>=1024

    // ---------- phase 1: z, r ----------
    f32x4 az0 = {0.f,0.f,0.f,0.f}, az1 = {0.f,0.f,0.f,0.f};
    f32x4 az2 = {0.f,0.f,0.f,0.f}, az3 = {0.f,0.f,0.f,0.f};
    f32x4 ar0 = {0.f,0.f,0.f,0.f}, ar1 = {0.f,0.f,0.f,0.f};
    f32x4 ar2 = {0.f,0.f,0.f,0.f}, ar3 = {0.f,0.f,0.f,0.f};
    // x-part — runs inside the detect window, off the serial chain
#pragma unroll
    for (int kt = 32; kt < 40; ++kt) {
      int k = kt * 32 + ko;
      bf8 a = *(const bf8*)(xrow + k);
      az0 = MFMA(a, *(const bf8*)(wzp + k), az0, 0, 0, 0);
      ar0 = MFMA(a, *(const bf8*)(wrp + k), ar0, 0, 0, 0);
    }
    waitflags(flags + lane, 2 * s);              // all h16(s-1) at LLC
    acq();                                       // ONE invalidate post-detect
    {
      const short* hb = h16 + bA * 1024 + ko;
      bf8 a[32];
#pragma unroll
      for (int t = 0; t < 32; ++t) a[t] = *(const bf8*)(hb + t * 32);
      __builtin_amdgcn_sched_barrier(0);         // all 32 loads issued first
#pragma unroll
      for (int t = 0; t < 32; t += 4) {
        int k0 = t * 32 + ko;
        az0 = MFMA(a[t],     *(const bf8*)(wzp + k0),      az0, 0, 0, 0);
        az1 = MFMA(a[t + 1], *(const bf8*)(wzp + k0 + 32), az1, 0, 0, 0);
        az2 = MFMA(a[t + 2], *(const bf8*)(wzp + k0 + 64), az2, 0, 0, 0);
        az3 = MFMA(a[t + 3], *(const bf8*)(wzp + k0 + 96), az3, 0, 0, 0);
        ar0 = MFMA(a[t],     *(const bf8*)(wrp + k0),      ar0, 0, 0, 0);
        ar1 = MFMA(a[t + 1], *(const bf8*)(wrp + k0 + 32), ar1, 0, 0, 0);
        ar2 = MFMA(a[t + 2], *(const bf8*)(wrp + k0 + 64), ar2, 0, 0, 0);
        ar3 = MFMA(a[t + 3], *(const bf8*)(wrp + k0 + 96), ar3, 0, 0, 0);
      }
    }
    f32x4 azs = (az0 + az1) + (az2 + az3);
    f32x4 ars = (ar0 + ar1) + (ar2 + ar3);
#pragma unroll
    for (int i = 0; i < 4; ++i) {
      zreg[i] = sigm(azs[i] + bzv);
      float r = sigm(ars[i] + brv);
      sc[(quad * 4 + i) * 16 + row16] = f2b(r * hreg[i]);  // wave-private LDS
    }
    if (lane < 32) {                             // same wave: DS ops in-order
      int rr = lane >> 1, hh = lane & 1;
      bf8 v = *(const bf8*)(sc + rr * 16 + hh * 8);
      st_b128_llc(ab + (bg0 + rr) * 1024 + j0 + hh * 8, v);
      drain_vm();                                // data at LLC before flag
    }
    __syncthreads();                             // all waves drained
    if (tid == 0) st_i32_llc(flags + blockIdx.x, 2 * s + 1);

    // ---------- phase 2: n, h update ----------
    f32x4 an0 = {0.f,0.f,0.f,0.f}, an1 = {0.f,0.f,0.f,0.f};
    f32x4 an2 = {0.f,0.f,0.f,0.f}, an3 = {0.f,0.f,0.f,0.f};
#pragma unroll
    for (int kt = 32; kt < 40; ++kt) {
      int k = kt * 32 + ko;
      bf8 a = *(const bf8*)(xrow + k);
      an0 = MFMA(a, *(const bf8*)(wnp + k), an0, 0, 0, 0);
    }
    waitflags(flags + lane, 2 * s + 1);          // all ab(s) at LLC
    acq();
    {
      const short* abb = ab + bA * 1024 + ko;
      bf8 a[32];
#pragma unroll
      for (int t = 0; t < 32; ++t) a[t] = *(const bf8*)(abb + t * 32);
      __builtin_amdgcn_sched_barrier(0);
#pragma unroll
      for (int t = 0; t < 32; t += 4) {
        int k0 = t * 32 + ko;
        an0 = MFMA(a[t],     *(const bf8*)(wnp + k0),      an0, 0, 0, 0);
        an1 = MFMA(a[t + 1], *(const bf8*)(wnp + k0 + 32), an1, 0, 0, 0);
        an2 = MFMA(a[t + 2], *(const bf8*)(wnp + k0 + 64), an2, 0, 0, 0);
        an3 = MFMA(a[t + 3], *(const bf8*)(wnp + k0 + 96), an3, 0, 0, 0);
      }
    }
    f32x4 ans = (an0 + an1) + (an2 + an3);
#pragma unroll
    for (int i = 0; i < 4; ++i) {
      float n = tanh_(ans[i] + bhv);
      hreg[i] = fmaf(zreg[i], n - hreg[i], hreg[i]);   // (1-z)h + z*n
      sc[(quad * 4 + i) * 16 + row16] = f2b(hreg[i]);
      if (s == 511)
        st_f32_llc(&h32[(bg0 + quad * 4 + i) * 1024 + j0 + row16], hreg[i]);
    }
    if (lane < 32) {
      int rr = lane >> 1, hh = lane & 1;
      bf8 v = *(const bf8*)(sc + rr * 16 + hh * 8);
      st_b128_llc(h16 + (bg0 + rr) * 1024 + j0 + hh * 8, v);
      drain_vm();
    }
    __syncthreads();
    if (tid == 0) st_i32_llc(flags + blockIdx.x, 2 * s + 2);
  }

  // ---------- head: out[b][o] = sum_k h32[b][k]*Wf[k][o] + bf[o] ----------
  waitflags(flags + lane, 1024);
  acq();
  {
    const float* hrow = h32 + blockIdx.x * 1024;
    float acc = bfv[tid];
#pragma unroll 8
    for (int k = 0; k < 1024; ++k)
      acc = fmaf(hrow[k], Wf[(size_t)k * 256 + tid], acc);
    out[blockIdx.x * 256 + tid] = acc;
  }
}

// ---------------- host ----------------
extern "C" void kernel_launch(void* const* d_in, const int* in_sizes, int n_in,
                              void* d_out, int out_size, void* d_ws, size_t ws_size,
                              hipStream_t stream) {
  const float* x   = (const float*)d_in[0];
  const float* Wxz = (const float*)d_in[1];
  const float* Whz = (const float*)d_in[2];
  const float* Wxr = (const float*)d_in[3];
  const float* Whr = (const float*)d_in[4];
  const float* Wxh = (const float*)d_in[5];
  const float* Whh = (const float*)d_in[6];
  const float* bz  = (const float*)d_in[7];
  const float* br  = (const float*)d_in[8];
  const float* bh  = (const float*)d_in[9];
  const float* Wf  = (const float*)d_in[10];
  const float* bfp = (const float*)d_in[11];
  float* out = (float*)d_out;

  char* ws = (char*)d_ws;
  float* h32 = (float*)(ws + 0);            // 256 KB
  short* h16 = (short*)(ws + 262144);       // 128 KB
  int*   flg = (int*)  (ws + 393216);       // 4 KB (64 flags used)
  short* ab  = (short*)(ws + 397312);       // 128 KB
  short* xx  = (short*)(ws + 528384);       // 16 MB
  short* Wt  = (short*)(ws + 17305600);     // 7.86 MB (total ~24 MB)

  hipMemsetAsync(d_ws, 0, 397312, stream);  // h32 + h16 + flags = zeros

  cvt_x<<<8192, 256, 0, stream>>>(x, xx);
  pack_w<<<960, 256, 0, stream>>>(Whz, Wxz, Whr, Wxr, Whh, Wxh, Wt);

  const int smem = (48 * KP + 4 * 256) * 2; // 125,696 B
  hipFuncSetAttribute((const void*)gru_persistent,
                      hipFuncAttributeMaxDynamicSharedMemorySize, smem);
  void* args[] = {&xx, &Wt, &h32, &h16, &ab, &flg,
                  (void*)&bz, (void*)&br, (void*)&bh, (void*)&Wf, (void*)&bfp, &out};
  hipLaunchCooperativeKernel((const void*)gru_persistent, dim3(64), dim3(256),
                             args, smem, stream);
}

// Round 8
// 7451.557 us; speedup vs baseline: 1.6895x; 1.0744x over previous
//
#include <hip/hip_runtime.h>
#include <math.h>

// GRU: B=64, S=512, I=256, H=1024, O=256.
// Round 11 = Round 10 resubmitted verbatim (R10's bench was an infra flake:
// "container failed twice", no pytest/compile signal ever produced).
// R10 = R8 (proven 8006us) + per-wave band chains, remat-safe.
//   - R9 failure root cause: the r/z split kept load-derived regs (a[32])
//     live ACROSS the flag post; h16 was __restrict and the exchange stores
//     are asm through other pointers, so the compiler could legally remat/
//     sink those loads past the post — reading h(s) after other blocks
//     overwrote it. (R7 passed with banding+no-split => banding is fine;
//     R8 passed with split-free lockstep => consumption-before-post is fine.)
//   - Fix #1 (structural): z fused with r BEFORE the post (R8 form). Every
//     exchange load is consumed before any post — sinking is blocked by
//     data dependence alone.
//   - Fix #2 (defense): h16/ab are NOT __restrict anymore — asm stores are
//     potential clobbers, remat across them is illegal.
//   - Banding: flags[band*64+block]; wave w posts/polls only band w. The 4
//     bands are independent 64-wave barrier systems (one per SIMD) that
//     drift and pipeline; no __syncthreads in the loop; per-wave drain.
//   - Kept from R8: deep a[32] burst + sched_barrier(0), pipelined 2-deep
//     sc0sc1 poll (one asm block), acq ONCE after detect, x-proj at phase
//     start (detect window), 4 MFMA accumulators/gate, wave-private LDS
//     transpose + 16B sc0sc1 exchange stores, drain before post.

#define KP 1288   // LDS K-stride (elems): 2576 B, 16B aligned

typedef __attribute__((ext_vector_type(8))) short bf8;
typedef __attribute__((ext_vector_type(4))) short bf4;
typedef __attribute__((ext_vector_type(4))) float f32x4;

__device__ __forceinline__ short f2b(float f) {
  unsigned u = __builtin_bit_cast(unsigned, f);
  u += 0x7fffu + ((u >> 16) & 1u);          // RNE
  return (short)(u >> 16);
}
__device__ __forceinline__ float sigm(float x) { return 1.f / (1.f + __expf(-x)); }
__device__ __forceinline__ float tanh_(float x) {
  float t = fminf(fmaxf(x, -12.f), 12.f);
  float e = __expf(2.f * t);
  return (e - 1.f) / (e + 1.f);
}

// ---- LLC write-through stores (visible at coherence point cross-XCD) ----
__device__ __forceinline__ void st_b128_llc(short* p, bf8 v) {
  asm volatile("global_store_dwordx4 %0, %1, off sc0 sc1"
               :: "v"(p), "v"(v) : "memory");
}
__device__ __forceinline__ void st_f32_llc(float* p, float v) {
  asm volatile("global_store_dword %0, %1, off sc0 sc1"
               :: "v"(p), "v"(v) : "memory");
}
__device__ __forceinline__ void st_i32_llc(int* p, int v) {
  asm volatile("global_store_dword %0, %1, off sc0 sc1"
               :: "v"(p), "v"(v) : "memory");
}
__device__ __forceinline__ void drain_vm() {
  asm volatile("s_waitcnt vmcnt(0)" ::: "memory");
}
__device__ __forceinline__ void acq() {
  __builtin_amdgcn_fence(__ATOMIC_ACQUIRE, "agent");   // buffer_inv, ONCE
}
// Pipelined poll, fully inside one asm block (no compiler spill hazard).
// Two poll loads in flight; check one while the other travels. sc0sc1 loads
// read the coherence point (never stale, no cache invalidation).
__device__ __forceinline__ void waitflags(const int* fp, int p) {
  int f0, f1;
  asm volatile(
      "global_load_dword %0, %2, off sc0 sc1\n"
      "1:\n"
      "global_load_dword %1, %2, off sc0 sc1\n"
      "s_waitcnt vmcnt(1)\n"
      "v_cmp_lt_i32 vcc, %0, %3\n"
      "s_cbranch_vccz 2f\n"
      "global_load_dword %0, %2, off sc0 sc1\n"
      "s_waitcnt vmcnt(1)\n"
      "v_cmp_lt_i32 vcc, %1, %3\n"
      "s_cbranch_vccz 2f\n"
      "s_branch 1b\n"
      "2:\n"
      "s_waitcnt vmcnt(0)\n"
      : "=&v"(f0), "=&v"(f1)
      : "v"(fp), "v"(p)
      : "vcc", "memory");
}

#define MFMA __builtin_amdgcn_mfma_f32_16x16x32_bf16

// ---------------- preprocessing ----------------

__global__ __launch_bounds__(256) void cvt_x(const float* __restrict__ in,
                                             short* __restrict__ outp) {
  int idx = blockIdx.x * 256 + threadIdx.x;        // 8192 blocks, 4 floats each
  float4 v = ((const float4*)in)[idx];
  bf4 o;
  o[0] = f2b(v.x); o[1] = f2b(v.y); o[2] = f2b(v.z); o[3] = f2b(v.w);
  ((bf4*)outp)[idx] = o;
}

// Wt[g][j][k] = bf16( k<1024 ? Wh_g[k][j] : Wx_g[k-1024][j] ), k=0..1279.
__global__ __launch_bounds__(256) void pack_w(
    const float* __restrict__ Whz, const float* __restrict__ Wxz,
    const float* __restrict__ Whr, const float* __restrict__ Wxr,
    const float* __restrict__ Whh, const float* __restrict__ Wxh,
    short* __restrict__ Wt) {
  int b = blockIdx.x;
  int g = b / 320, rem = b % 320;
  int jt = rem / 20, kt = rem % 20;
  int j0 = jt * 64, k0 = kt * 64;
  const float* Wh = (g == 0) ? Whz : (g == 1) ? Whr : Whh;
  const float* Wx = (g == 0) ? Wxz : (g == 1) ? Wxr : Wxh;
  __shared__ short tile[64 * 72];
  int tid = threadIdx.x;
  for (int p = 0; p < 16; ++p) {
    int r = p * 4 + (tid >> 6);
    int cc = tid & 63;
    int k = k0 + r;
    float v = (k < 1024) ? Wh[(size_t)k * 1024 + j0 + cc]
                         : Wx[(size_t)(k - 1024) * 1024 + j0 + cc];
    tile[r * 72 + cc] = f2b(v);
  }
  __syncthreads();
  int j = tid >> 2, kq = tid & 3;
  bf8 v0, v1;
#pragma unroll
  for (int i = 0; i < 8; ++i) {
    v0[i] = tile[(kq * 16 + i) * 72 + j];
    v1[i] = tile[(kq * 16 + 8 + i) * 72 + j];
  }
  short* dst = Wt + ((size_t)(g * 1024 + j0 + j)) * 1280 + k0 + kq * 16;
  *(bf8*)dst = v0;
  *((bf8*)dst + 1) = v1;
}

// ---------------- persistent GRU kernel ----------------
__global__ __launch_bounds__(256, 1) void gru_persistent(
    const short* __restrict__ xx,   // x bf16 [64][512][256]
    const short* __restrict__ Wt,   // packed weights bf16 [3][1024][1280]
    float* __restrict__ h32,        // fp32 h final [64][1024] (written s=511)
    short* h16,                     // bf16 h (exchange) — NO restrict (remat)
    short* ab,                      // bf16 r*h (exchange) — NO restrict
    int* __restrict__ flags,        // [band][block] per-wave progress flags
    const float* __restrict__ bz, const float* __restrict__ br,
    const float* __restrict__ bh,
    const float* __restrict__ Wf, const float* __restrict__ bfv,
    float* __restrict__ out) {
  extern __shared__ short lds[];                 // 48*KP weights + 4*256 scratch

  const int tid = threadIdx.x;
  const int w = tid >> 6, lane = tid & 63;
  const int row16 = lane & 15, quad = lane >> 4;
  const int j0 = blockIdx.x * 16;
  const int bg0 = w * 16;
  const int bA = bg0 + row16;                    // batch row for A-loads

  const float bzv = bz[j0 + row16];
  const float brv = br[j0 + row16];
  const float bhv = bh[j0 + row16];

  // weights -> LDS (48 cols x 1280, transposed, bf16)
  for (int ch = tid; ch < 48 * 160; ch += 256) {
    int lc = ch / 160, c8 = ch % 160;
    int g = lc >> 4, j = j0 + (lc & 15);
    *(bf8*)(lds + lc * KP + c8 * 8) =
        *(const bf8*)(Wt + ((size_t)(g * 1024 + j)) * 1280 + c8 * 8);
  }
  __syncthreads();                               // only block-wide sync

  const short* wzp = lds + row16 * KP;
  const short* wrp = lds + (16 + row16) * KP;
  const short* wnp = lds + (32 + row16) * KP;
  short* sc = lds + 48 * KP + w * 256;           // wave-private 16x16 tile
  const int ko = quad * 8;

  const int* fpoll = flags + w * 64 + lane;      // band w, flag of block=lane
  int* mypost = flags + w * 64 + blockIdx.x;

  float hreg[4] = {0.f, 0.f, 0.f, 0.f};          // fp32 h, lives in regs
  float zreg[4];

  for (int s = 0; s < 512; ++s) {
    const short* xrow = xx + (bA * 512 + s) * 256 - 1024;  // +k valid k>=1024

    // ---------- phase 1: z, r ----------
    f32x4 az0 = {0.f,0.f,0.f,0.f}, az1 = {0.f,0.f,0.f,0.f};
    f32x4 az2 = {0.f,0.f,0.f,0.f}, az3 = {0.f,0.f,0.f,0.f};
    f32x4 ar0 = {0.f,0.f,0.f,0.f}, ar1 = {0.f,0.f,0.f,0.f};
    f32x4 ar2 = {0.f,0.f,0.f,0.f}, ar3 = {0.f,0.f,0.f,0.f};
    // x-part — inside the detect window, off the serial chain
#pragma unroll
    for (int kt = 32; kt < 40; ++kt) {
      int k = kt * 32 + ko;
      bf8 a = *(const bf8*)(xrow + k);
      az0 = MFMA(a, *(const bf8*)(wzp + k), az0, 0, 0, 0);
      ar0 = MFMA(a, *(const bf8*)(wrp + k), ar0, 0, 0, 0);
    }
    waitflags(fpoll, 2 * s);                     // band's h16(s-1) at LLC
    acq();                                       // ONE invalidate post-detect
    {
      const short* hb = h16 + bA * 1024 + ko;
      bf8 a[32];
#pragma unroll
      for (int t = 0; t < 32; ++t) a[t] = *(const bf8*)(hb + t * 32);
      __builtin_amdgcn_sched_barrier(0);         // all 32 loads issued first
      // z AND r h-parts — all of a[] consumed BEFORE the post (no remat
      // window; data dependence pins loads ahead of stores/post)
#pragma unroll
      for (int t = 0; t < 32; t += 4) {
        int k0 = t * 32 + ko;
        az0 = MFMA(a[t],     *(const bf8*)(wzp + k0),      az0, 0, 0, 0);
        az1 = MFMA(a[t + 1], *(const bf8*)(wzp + k0 + 32), az1, 0, 0, 0);
        az2 = MFMA(a[t + 2], *(const bf8*)(wzp + k0 + 64), az2, 0, 0, 0);
        az3 = MFMA(a[t + 3], *(const bf8*)(wzp + k0 + 96), az3, 0, 0, 0);
        ar0 = MFMA(a[t],     *(const bf8*)(wrp + k0),      ar0, 0, 0, 0);
        ar1 = MFMA(a[t + 1], *(const bf8*)(wrp + k0 + 32), ar1, 0, 0, 0);
        ar2 = MFMA(a[t + 2], *(const bf8*)(wrp + k0 + 64), ar2, 0, 0, 0);
        ar3 = MFMA(a[t + 3], *(const bf8*)(wrp + k0 + 96), ar3, 0, 0, 0);
      }
    }
    f32x4 azs = (az0 + az1) + (az2 + az3);
    f32x4 ars = (ar0 + ar1) + (ar2 + ar3);
#pragma unroll
    for (int i = 0; i < 4; ++i) {
      zreg[i] = sigm(azs[i] + bzv);
      float r = sigm(ars[i] + brv);
      sc[(quad * 4 + i) * 16 + row16] = f2b(r * hreg[i]);  // wave-private LDS
    }
    if (lane < 32) {                             // same wave: DS ops in-order
      int rr = lane >> 1, hh = lane & 1;
      bf8 v = *(const bf8*)(sc + rr * 16 + hh * 8);
      st_b128_llc(ab + (bg0 + rr) * 1024 + j0 + hh * 8, v);
      drain_vm();                                // data at LLC before flag
    }
    if (lane == 0) st_i32_llc(mypost, 2 * s + 1);

    // ---------- phase 2: n, h update ----------
    f32x4 an0 = {0.f,0.f,0.f,0.f}, an1 = {0.f,0.f,0.f,0.f};
    f32x4 an2 = {0.f,0.f,0.f,0.f}, an3 = {0.f,0.f,0.f,0.f};
#pragma unroll
    for (int kt = 32; kt < 40; ++kt) {
      int k = kt * 32 + ko;
      bf8 x = *(const bf8*)(xrow + k);
      an0 = MFMA(x, *(const bf8*)(wnp + k), an0, 0, 0, 0);
    }
    waitflags(fpoll, 2 * s + 1);                 // band's ab(s) at LLC
    acq();
    {
      const short* abb = ab + bA * 1024 + ko;
      bf8 a[32];
#pragma unroll
      for (int t = 0; t < 32; ++t) a[t] = *(const bf8*)(abb + t * 32);
      __builtin_amdgcn_sched_barrier(0);
#pragma unroll
      for (int t = 0; t < 32; t += 4) {
        int k0 = t * 32 + ko;
        an0 = MFMA(a[t],     *(const bf8*)(wnp + k0),      an0, 0, 0, 0);
        an1 = MFMA(a[t + 1], *(const bf8*)(wnp + k0 + 32), an1, 0, 0, 0);
        an2 = MFMA(a[t + 2], *(const bf8*)(wnp + k0 + 64), an2, 0, 0, 0);
        an3 = MFMA(a[t + 3], *(const bf8*)(wnp + k0 + 96), an3, 0, 0, 0);
      }
    }
    f32x4 ans = (an0 + an1) + (an2 + an3);
#pragma unroll
    for (int i = 0; i < 4; ++i) {
      float n = tanh_(ans[i] + bhv);
      hreg[i] = fmaf(zreg[i], n - hreg[i], hreg[i]);   // (1-z)h + z*n
      sc[(quad * 4 + i) * 16 + row16] = f2b(hreg[i]);
      if (s == 511)
        st_f32_llc(&h32[(bg0 + quad * 4 + i) * 1024 + j0 + row16], hreg[i]);
    }
    if (lane < 32) {
      int rr = lane >> 1, hh = lane & 1;
      bf8 v = *(const bf8*)(sc + rr * 16 + hh * 8);
      st_b128_llc(h16 + (bg0 + rr) * 1024 + j0 + hh * 8, v);
      drain_vm();                                // h16 (+h32) stores at LLC
    }
    if (lane == 0) st_i32_llc(mypost, 2 * s + 2);
  }

  // ---------- head: out[b][o] = sum_k h32[b][k]*Wf[k][o] + bf[o] ----------
  waitflags(flags + ((blockIdx.x >> 4) << 6) + lane, 1024);  // h32 band done
  acq();
  {
    const float* hrow = h32 + blockIdx.x * 1024;
    float acc = bfv[tid];
#pragma unroll 8
    for (int k = 0; k < 1024; ++k)
      acc = fmaf(hrow[k], Wf[(size_t)k * 256 + tid], acc);
    out[blockIdx.x * 256 + tid] = acc;
  }
}

// ---------------- host ----------------
extern "C" void kernel_launch(void* const* d_in, const int* in_sizes, int n_in,
                              void* d_out, int out_size, void* d_ws, size_t ws_size,
                              hipStream_t stream) {
  const float* x   = (const float*)d_in[0];
  const float* Wxz = (const float*)d_in[1];
  const float* Whz = (const float*)d_in[2];
  const float* Wxr = (const float*)d_in[3];
  const float* Whr = (const float*)d_in[4];
  const float* Wxh = (const float*)d_in[5];
  const float* Whh = (const float*)d_in[6];
  const float* bz  = (const float*)d_in[7];
  const float* br  = (const float*)d_in[8];
  const float* bh  = (const float*)d_in[9];
  const float* Wf  = (const float*)d_in[10];
  const float* bfp = (const float*)d_in[11];
  float* out = (float*)d_out;

  char* ws = (char*)d_ws;
  float* h32 = (float*)(ws + 0);            // 256 KB
  short* h16 = (short*)(ws + 262144);       // 128 KB
  int*   flg = (int*)  (ws + 393216);       // 1 KB used (256 flags)
  short* ab  = (short*)(ws + 397312);       // 128 KB
  short* xx  = (short*)(ws + 528384);       // 16 MB
  short* Wt  = (short*)(ws + 17305600);     // 7.86 MB (total ~24 MB)

  hipMemsetAsync(d_ws, 0, 397312, stream);  // h32 + h16 + flags = zeros

  cvt_x<<<8192, 256, 0, stream>>>(x, xx);
  pack_w<<<960, 256, 0, stream>>>(Whz, Wxz, Whr, Wxr, Whh, Wxh, Wt);

  const int smem = (48 * KP + 4 * 256) * 2; // 125,696 B
  hipFuncSetAttribute((const void*)gru_persistent,
                      hipFuncAttributeMaxDynamicSharedMemorySize, smem);
  void* args[] = {&xx, &Wt, &h32, &h16, &ab, &flg,
                  (void*)&bz, (void*)&br, (void*)&bh, (void*)&Wf, (void*)&bfp, &out};
  hipLaunchCooperativeKernel((const void*)gru_persistent, dim3(64), dim3(256),
                             args, smem, stream);
}

// Round 9
// 7078.976 us; speedup vs baseline: 1.7784x; 1.0526x over previous
//
#include <hip/hip_runtime.h>
#include <math.h>

// GRU: B=64, S=512, I=256, H=1024, O=256.
// Round 12 = R11 (proven 7452us) + acq() DELETED from the main loop.
//   - R11 counters: FETCH_SIZE stuck at ~600MB (= ~585KB/phase) across all
//     protocol variants => the per-phase agent-acquire (buffer_inv) wipes the
//     XCD L2 every phase and the working set (x slices etc.) refetches from
//     LLC/HBM — twice on the chain (inv cost + x-proj loads turned into
//     misses that delay entering waitflags).
//   - Fix: exchange reads become sc0sc1 loads (read the coherence point
//     directly, like the polls — never stale, no invalidation needed).
//     Sound form (R4 failed this): ONE asm block = 32x global_load_dwordx4
//     sc0sc1 off one base + imm offsets, s_waitcnt vmcnt(0) at end, 32
//     early-clobber 16B outputs. Atomic to the compiler: no spill window,
//     guaranteed 32-deep burst. No acq in the loop; ONE acq before head.
//   - Flags spaced 16B apart (fills the existing 4KB hole): 4x fewer flags
//     per LLC line => less post/poll slice contention.
//   - Everything else identical to R11 (banding, pipelined poll, x-proj in
//     detect window, z+r fused pre-post, LDS transpose, 16B stores, drain
//     before post).

#define KP 1288   // LDS K-stride (elems): 2576 B, 16B aligned

typedef __attribute__((ext_vector_type(8))) short bf8;
typedef __attribute__((ext_vector_type(4))) short bf4;
typedef __attribute__((ext_vector_type(4))) float f32x4;

__device__ __forceinline__ short f2b(float f) {
  unsigned u = __builtin_bit_cast(unsigned, f);
  u += 0x7fffu + ((u >> 16) & 1u);          // RNE
  return (short)(u >> 16);
}
__device__ __forceinline__ float sigm(float x) { return 1.f / (1.f + __expf(-x)); }
__device__ __forceinline__ float tanh_(float x) {
  float t = fminf(fmaxf(x, -12.f), 12.f);
  float e = __expf(2.f * t);
  return (e - 1.f) / (e + 1.f);
}

// ---- LLC write-through stores (visible at coherence point cross-XCD) ----
__device__ __forceinline__ void st_b128_llc(short* p, bf8 v) {
  asm volatile("global_store_dwordx4 %0, %1, off sc0 sc1"
               :: "v"(p), "v"(v) : "memory");
}
__device__ __forceinline__ void st_f32_llc(float* p, float v) {
  asm volatile("global_store_dword %0, %1, off sc0 sc1"
               :: "v"(p), "v"(v) : "memory");
}
__device__ __forceinline__ void st_i32_llc(int* p, int v) {
  asm volatile("global_store_dword %0, %1, off sc0 sc1"
               :: "v"(p), "v"(v) : "memory");
}
__device__ __forceinline__ void drain_vm() {
  asm volatile("s_waitcnt vmcnt(0)" ::: "memory");
}
__device__ __forceinline__ void acq() {
  __builtin_amdgcn_fence(__ATOMIC_ACQUIRE, "agent");   // head only
}
// Pipelined poll, fully inside one asm block (no compiler spill hazard).
__device__ __forceinline__ void waitflags(const int* fp, int p) {
  int f0, f1;
  asm volatile(
      "global_load_dword %0, %2, off sc0 sc1\n"
      "1:\n"
      "global_load_dword %1, %2, off sc0 sc1\n"
      "s_waitcnt vmcnt(1)\n"
      "v_cmp_lt_i32 vcc, %0, %3\n"
      "s_cbranch_vccz 2f\n"
      "global_load_dword %0, %2, off sc0 sc1\n"
      "s_waitcnt vmcnt(1)\n"
      "v_cmp_lt_i32 vcc, %1, %3\n"
      "s_cbranch_vccz 2f\n"
      "s_branch 1b\n"
      "2:\n"
      "s_waitcnt vmcnt(0)\n"
      : "=&v"(f0), "=&v"(f1)
      : "v"(fp), "v"(p)
      : "vcc", "memory");
}

// 32x16B sc0sc1 burst from one base, all in flight, valid at asm exit.
// LLC-direct: never allocates in L1/L2, so no acquire fence is needed.
#define LLC_BURST32(dst, base)                                              \
  asm volatile(                                                             \
      "global_load_dwordx4 %0, %32, off sc0 sc1\n"                          \
      "global_load_dwordx4 %1, %32, off offset:64 sc0 sc1\n"                \
      "global_load_dwordx4 %2, %32, off offset:128 sc0 sc1\n"               \
      "global_load_dwordx4 %3, %32, off offset:192 sc0 sc1\n"               \
      "global_load_dwordx4 %4, %32, off offset:256 sc0 sc1\n"               \
      "global_load_dwordx4 %5, %32, off offset:320 sc0 sc1\n"               \
      "global_load_dwordx4 %6, %32, off offset:384 sc0 sc1\n"               \
      "global_load_dwordx4 %7, %32, off offset:448 sc0 sc1\n"               \
      "global_load_dwordx4 %8, %32, off offset:512 sc0 sc1\n"               \
      "global_load_dwordx4 %9, %32, off offset:576 sc0 sc1\n"               \
      "global_load_dwordx4 %10, %32, off offset:640 sc0 sc1\n"              \
      "global_load_dwordx4 %11, %32, off offset:704 sc0 sc1\n"              \
      "global_load_dwordx4 %12, %32, off offset:768 sc0 sc1\n"              \
      "global_load_dwordx4 %13, %32, off offset:832 sc0 sc1\n"              \
      "global_load_dwordx4 %14, %32, off offset:896 sc0 sc1\n"              \
      "global_load_dwordx4 %15, %32, off offset:960 sc0 sc1\n"              \
      "global_load_dwordx4 %16, %32, off offset:1024 sc0 sc1\n"             \
      "global_load_dwordx4 %17, %32, off offset:1088 sc0 sc1\n"             \
      "global_load_dwordx4 %18, %32, off offset:1152 sc0 sc1\n"             \
      "global_load_dwordx4 %19, %32, off offset:1216 sc0 sc1\n"             \
      "global_load_dwordx4 %20, %32, off offset:1280 sc0 sc1\n"             \
      "global_load_dwordx4 %21, %32, off offset:1344 sc0 sc1\n"             \
      "global_load_dwordx4 %22, %32, off offset:1408 sc0 sc1\n"             \
      "global_load_dwordx4 %23, %32, off offset:1472 sc0 sc1\n"             \
      "global_load_dwordx4 %24, %32, off offset:1536 sc0 sc1\n"             \
      "global_load_dwordx4 %25, %32, off offset:1600 sc0 sc1\n"             \
      "global_load_dwordx4 %26, %32, off offset:1664 sc0 sc1\n"             \
      "global_load_dwordx4 %27, %32, off offset:1728 sc0 sc1\n"             \
      "global_load_dwordx4 %28, %32, off offset:1792 sc0 sc1\n"             \
      "global_load_dwordx4 %29, %32, off offset:1856 sc0 sc1\n"             \
      "global_load_dwordx4 %30, %32, off offset:1920 sc0 sc1\n"             \
      "global_load_dwordx4 %31, %32, off offset:1984 sc0 sc1\n"             \
      "s_waitcnt vmcnt(0)\n"                                                \
      : "=&v"(dst[0]), "=&v"(dst[1]), "=&v"(dst[2]), "=&v"(dst[3]),         \
        "=&v"(dst[4]), "=&v"(dst[5]), "=&v"(dst[6]), "=&v"(dst[7]),         \
        "=&v"(dst[8]), "=&v"(dst[9]), "=&v"(dst[10]), "=&v"(dst[11]),       \
        "=&v"(dst[12]), "=&v"(dst[13]), "=&v"(dst[14]), "=&v"(dst[15]),     \
        "=&v"(dst[16]), "=&v"(dst[17]), "=&v"(dst[18]), "=&v"(dst[19]),     \
        "=&v"(dst[20]), "=&v"(dst[21]), "=&v"(dst[22]), "=&v"(dst[23]),     \
        "=&v"(dst[24]), "=&v"(dst[25]), "=&v"(dst[26]), "=&v"(dst[27]),     \
        "=&v"(dst[28]), "=&v"(dst[29]), "=&v"(dst[30]), "=&v"(dst[31])      \
      : "v"(base)                                                           \
      : "memory")

#define MFMA __builtin_amdgcn_mfma_f32_16x16x32_bf16

// ---------------- preprocessing ----------------

__global__ __launch_bounds__(256) void cvt_x(const float* __restrict__ in,
                                             short* __restrict__ outp) {
  int idx = blockIdx.x * 256 + threadIdx.x;        // 8192 blocks, 4 floats each
  float4 v = ((const float4*)in)[idx];
  bf4 o;
  o[0] = f2b(v.x); o[1] = f2b(v.y); o[2] = f2b(v.z); o[3] = f2b(v.w);
  ((bf4*)outp)[idx] = o;
}

// Wt[g][j][k] = bf16( k<1024 ? Wh_g[k][j] : Wx_g[k-1024][j] ), k=0..1279.
__global__ __launch_bounds__(256) void pack_w(
    const float* __restrict__ Whz, const float* __restrict__ Wxz,
    const float* __restrict__ Whr, const float* __restrict__ Wxr,
    const float* __restrict__ Whh, const float* __restrict__ Wxh,
    short* __restrict__ Wt) {
  int b = blockIdx.x;
  int g = b / 320, rem = b % 320;
  int jt = rem / 20, kt = rem % 20;
  int j0 = jt * 64, k0 = kt * 64;
  const float* Wh = (g == 0) ? Whz : (g == 1) ? Whr : Whh;
  const float* Wx = (g == 0) ? Wxz : (g == 1) ? Wxr : Wxh;
  __shared__ short tile[64 * 72];
  int tid = threadIdx.x;
  for (int p = 0; p < 16; ++p) {
    int r = p * 4 + (tid >> 6);
    int cc = tid & 63;
    int k = k0 + r;
    float v = (k < 1024) ? Wh[(size_t)k * 1024 + j0 + cc]
                         : Wx[(size_t)(k - 1024) * 1024 + j0 + cc];
    tile[r * 72 + cc] = f2b(v);
  }
  __syncthreads();
  int j = tid >> 2, kq = tid & 3;
  bf8 v0, v1;
#pragma unroll
  for (int i = 0; i < 8; ++i) {
    v0[i] = tile[(kq * 16 + i) * 72 + j];
    v1[i] = tile[(kq * 16 + 8 + i) * 72 + j];
  }
  short* dst = Wt + ((size_t)(g * 1024 + j0 + j)) * 1280 + k0 + kq * 16;
  *(bf8*)dst = v0;
  *((bf8*)dst + 1) = v1;
}

// ---------------- persistent GRU kernel ----------------
__global__ __launch_bounds__(256, 1) void gru_persistent(
    const short* __restrict__ xx,   // x bf16 [64][512][256]
    const short* __restrict__ Wt,   // packed weights bf16 [3][1024][1280]
    float* __restrict__ h32,        // fp32 h final [64][1024] (written s=511)
    short* h16,                     // bf16 h (exchange)
    short* ab,                      // bf16 r*h (exchange)
    int* __restrict__ flags,       // [band][block] flags, 16B-spaced
    const float* __restrict__ bz, const float* __restrict__ br,
    const float* __restrict__ bh,
    const float* __restrict__ Wf, const float* __restrict__ bfv,
    float* __restrict__ out) {
  extern __shared__ short lds[];                 // 48*KP weights + 4*256 scratch

  const int tid = threadIdx.x;
  const int w = tid >> 6, lane = tid & 63;
  const int row16 = lane & 15, quad = lane >> 4;
  const int j0 = blockIdx.x * 16;
  const int bg0 = w * 16;
  const int bA = bg0 + row16;                    // batch row for A-loads

  const float bzv = bz[j0 + row16];
  const float brv = br[j0 + row16];
  const float bhv = bh[j0 + row16];

  // weights -> LDS (48 cols x 1280, transposed, bf16)
  for (int ch = tid; ch < 48 * 160; ch += 256) {
    int lc = ch / 160, c8 = ch % 160;
    int g = lc >> 4, j = j0 + (lc & 15);
    *(bf8*)(lds + lc * KP + c8 * 8) =
        *(const bf8*)(Wt + ((size_t)(g * 1024 + j)) * 1280 + c8 * 8);
  }
  __syncthreads();                               // only block-wide sync

  const short* wzp = lds + row16 * KP;
  const short* wrp = lds + (16 + row16) * KP;
  const short* wnp = lds + (32 + row16) * KP;
  short* sc = lds + 48 * KP + w * 256;           // wave-private 16x16 tile
  const int ko = quad * 8;

  const int* fpoll = flags + (w * 64 + lane) * 4;      // 16B-spaced flags
  int* mypost = flags + (w * 64 + blockIdx.x) * 4;

  float hreg[4] = {0.f, 0.f, 0.f, 0.f};          // fp32 h, lives in regs
  float zreg[4];

  for (int s = 0; s < 512; ++s) {
    const short* xrow = xx + (bA * 512 + s) * 256 - 1024;  // +k valid k>=1024

    // ---------- phase 1: z, r ----------
    f32x4 az0 = {0.f,0.f,0.f,0.f}, az1 = {0.f,0.f,0.f,0.f};
    f32x4 az2 = {0.f,0.f,0.f,0.f}, az3 = {0.f,0.f,0.f,0.f};
    f32x4 ar0 = {0.f,0.f,0.f,0.f}, ar1 = {0.f,0.f,0.f,0.f};
    f32x4 ar2 = {0.f,0.f,0.f,0.f}, ar3 = {0.f,0.f,0.f,0.f};
    // x-part — L2-warm now (no acq), inside the detect window
#pragma unroll
    for (int kt = 32; kt < 40; ++kt) {
      int k = kt * 32 + ko;
      bf8 a = *(const bf8*)(xrow + k);
      az0 = MFMA(a, *(const bf8*)(wzp + k), az0, 0, 0, 0);
      ar0 = MFMA(a, *(const bf8*)(wrp + k), ar0, 0, 0, 0);
    }
    waitflags(fpoll, 2 * s);                     // band's h16(s-1) at LLC
    {
      bf8 a[32];
      LLC_BURST32(a, h16 + bA * 1024 + ko);      // LLC-direct, no acq
#pragma unroll
      for (int t = 0; t < 32; t += 4) {
        int k0 = t * 32 + ko;
        az0 = MFMA(a[t],     *(const bf8*)(wzp + k0),      az0, 0, 0, 0);
        az1 = MFMA(a[t + 1], *(const bf8*)(wzp + k0 + 32), az1, 0, 0, 0);
        az2 = MFMA(a[t + 2], *(const bf8*)(wzp + k0 + 64), az2, 0, 0, 0);
        az3 = MFMA(a[t + 3], *(const bf8*)(wzp + k0 + 96), az3, 0, 0, 0);
        ar0 = MFMA(a[t],     *(const bf8*)(wrp + k0),      ar0, 0, 0, 0);
        ar1 = MFMA(a[t + 1], *(const bf8*)(wrp + k0 + 32), ar1, 0, 0, 0);
        ar2 = MFMA(a[t + 2], *(const bf8*)(wrp + k0 + 64), ar2, 0, 0, 0);
        ar3 = MFMA(a[t + 3], *(const bf8*)(wrp + k0 + 96), ar3, 0, 0, 0);
      }
    }
    f32x4 azs = (az0 + az1) + (az2 + az3);
    f32x4 ars = (ar0 + ar1) + (ar2 + ar3);
#pragma unroll
    for (int i = 0; i < 4; ++i) {
      zreg[i] = sigm(azs[i] + bzv);
      float r = sigm(ars[i] + brv);
      sc[(quad * 4 + i) * 16 + row16] = f2b(r * hreg[i]);  // wave-private LDS
    }
    if (lane < 32) {                             // same wave: DS ops in-order
      int rr = lane >> 1, hh = lane & 1;
      bf8 v = *(const bf8*)(sc + rr * 16 + hh * 8);
      st_b128_llc(ab + (bg0 + rr) * 1024 + j0 + hh * 8, v);
      drain_vm();                                // data at LLC before flag
    }
    if (lane == 0) st_i32_llc(mypost, 2 * s + 1);

    // ---------- phase 2: n, h update ----------
    f32x4 an0 = {0.f,0.f,0.f,0.f}, an1 = {0.f,0.f,0.f,0.f};
    f32x4 an2 = {0.f,0.f,0.f,0.f}, an3 = {0.f,0.f,0.f,0.f};
#pragma unroll
    for (int kt = 32; kt < 40; ++kt) {
      int k = kt * 32 + ko;
      bf8 x = *(const bf8*)(xrow + k);
      an0 = MFMA(x, *(const bf8*)(wnp + k), an0, 0, 0, 0);
    }
    waitflags(fpoll, 2 * s + 1);                 // band's ab(s) at LLC
    {
      bf8 a[32];
      LLC_BURST32(a, ab + bA * 1024 + ko);
#pragma unroll
      for (int t = 0; t < 32; t += 4) {
        int k0 = t * 32 + ko;
        an0 = MFMA(a[t],     *(const bf8*)(wnp + k0),      an0, 0, 0, 0);
        an1 = MFMA(a[t + 1], *(const bf8*)(wnp + k0 + 32), an1, 0, 0, 0);
        an2 = MFMA(a[t + 2], *(const bf8*)(wnp + k0 + 64), an2, 0, 0, 0);
        an3 = MFMA(a[t + 3], *(const bf8*)(wnp + k0 + 96), an3, 0, 0, 0);
      }
    }
    f32x4 ans = (an0 + an1) + (an2 + an3);
#pragma unroll
    for (int i = 0; i < 4; ++i) {
      float n = tanh_(ans[i] + bhv);
      hreg[i] = fmaf(zreg[i], n - hreg[i], hreg[i]);   // (1-z)h + z*n
      sc[(quad * 4 + i) * 16 + row16] = f2b(hreg[i]);
      if (s == 511)
        st_f32_llc(&h32[(bg0 + quad * 4 + i) * 1024 + j0 + row16], hreg[i]);
    }
    if (lane < 32) {
      int rr = lane >> 1, hh = lane & 1;
      bf8 v = *(const bf8*)(sc + rr * 16 + hh * 8);
      st_b128_llc(h16 + (bg0 + rr) * 1024 + j0 + hh * 8, v);
      drain_vm();                                // h16 (+h32) stores at LLC
    }
    if (lane == 0) st_i32_llc(mypost, 2 * s + 2);
  }

  // ---------- head: out[b][o] = sum_k h32[b][k]*Wf[k][o] + bf[o] ----------
  waitflags(flags + (((blockIdx.x >> 4) << 6) + lane) * 4, 1024);
  acq();                                          // once: h32 via plain loads
  {
    const float* hrow = h32 + blockIdx.x * 1024;
    float acc = bfv[tid];
#pragma unroll 8
    for (int k = 0; k < 1024; ++k)
      acc = fmaf(hrow[k], Wf[(size_t)k * 256 + tid], acc);
    out[blockIdx.x * 256 + tid] = acc;
  }
}

// ---------------- host ----------------
extern "C" void kernel_launch(void* const* d_in, const int* in_sizes, int n_in,
                              void* d_out, int out_size, void* d_ws, size_t ws_size,
                              hipStream_t stream) {
  const float* x   = (const float*)d_in[0];
  const float* Wxz = (const float*)d_in[1];
  const float* Whz = (const float*)d_in[2];
  const float* Wxr = (const float*)d_in[3];
  const float* Whr = (const float*)d_in[4];
  const float* Wxh = (const float*)d_in[5];
  const float* Whh = (const float*)d_in[6];
  const float* bz  = (const float*)d_in[7];
  const float* br  = (const float*)d_in[8];
  const float* bh  = (const float*)d_in[9];
  const float* Wf  = (const float*)d_in[10];
  const float* bfp = (const float*)d_in[11];
  float* out = (float*)d_out;

  char* ws = (char*)d_ws;
  float* h32 = (float*)(ws + 0);            // 256 KB
  short* h16 = (short*)(ws + 262144);       // 128 KB
  int*   flg = (int*)  (ws + 393216);       // 4 KB (256 flags, 16B-spaced)
  short* ab  = (short*)(ws + 397312);       // 128 KB
  short* xx  = (short*)(ws + 528384);       // 16 MB
  short* Wt  = (short*)(ws + 17305600);     // 7.86 MB (total ~24 MB)

  hipMemsetAsync(d_ws, 0, 397312, stream);  // h32 + h16 + flags = zeros

  cvt_x<<<8192, 256, 0, stream>>>(x, xx);
  pack_w<<<960, 256, 0, stream>>>(Whz, Wxz, Whr, Wxr, Whh, Wxh, Wt);

  const int smem = (48 * KP + 4 * 256) * 2; // 125,696 B
  hipFuncSetAttribute((const void*)gru_persistent,
                      hipFuncAttributeMaxDynamicSharedMemorySize, smem);
  void* args[] = {&xx, &Wt, &h32, &h16, &ab, &flg,
                  (void*)&bz, (void*)&br, (void*)&bh, (void*)&Wf, (void*)&bfp, &out};
  hipLaunchCooperativeKernel((const void*)gru_persistent, dim3(64), dim3(256),
                             args, smem, stream);
}